// Round 9
// baseline (188.903 us; speedup 1.0000x reference)
//
#include <hip/hip_runtime.h>

typedef __attribute__((ext_vector_type(8))) short short8;
typedef __attribute__((ext_vector_type(8))) __bf16 bf16x8;
typedef __attribute__((ext_vector_type(4))) float f32x4;

// sizes
#define B_ 4
#define C_ 64
#define H_ 128
#define W_ 128
#define P_ (H_*W_)      // 16384
#define E_ 16

// ws layout (bytes)
#define OFF_XT   0u
#define XT_BYTES (4u*130u*130u*64u*2u)          // 8,652,800
#define OFF_A    8652800u
#define OFF_R1   9832448u
#define OFF_PARA 14026752u

__device__ inline unsigned short f2bf(float f) {
    union { float f; unsigned u; } v; v.f = f;
    unsigned r = v.u + 0x7FFF + ((v.u >> 16) & 1);
    return (unsigned short)(r >> 16);
}

// ---------- transpose+pad x (NCHW f32) -> xt[b][y+1][x+1][c] bf16 ----------
// Also zeroes the halo (left/right cols; rows 0/129 by the y==0/127 blocks).
__global__ __launch_bounds__(128) void k_transpose(const float* __restrict__ x,
                                                   unsigned short* __restrict__ xt) {
    int b = blockIdx.x >> 7, y = blockIdx.x & 127;
    int t = threadIdx.x; // x coordinate
    const float* src = x + (size_t)b * C_ * P_ + y * W_ + t;
    unsigned short* dst = xt + ((size_t)(b * 130 + y + 1) * 130 + t + 1) * 64;
#pragma unroll
    for (int i = 0; i < 8; ++i) {
        short8 v;
#pragma unroll
        for (int j = 0; j < 8; ++j) v[j] = (short)f2bf(src[(size_t)(i * 8 + j) * P_]);
        ((short8*)dst)[i] = v;
    }
    short8 z = {0,0,0,0,0,0,0,0};
    if (t < 16) {
        int col = (t >> 3) * 129, i = t & 7;
        unsigned short* bp = xt + ((size_t)(b * 130 + y + 1) * 130 + col) * 64;
        ((short8*)bp)[i] = z;
    }
    if (y == 0 || y == 127) {
        int prow = (y == 0) ? 0 : 129;
        unsigned short* rp = xt + (size_t)(b * 130 + prow) * 130 * 64;
        for (int ci = t; ci < 1040; ci += 128) ((short8*)rp)[ci] = z;
    }
}

// ---------- build A[row=o*16+e][col=(kh*3+kw)*64+c] bf16 from W ----------
__global__ __launch_bounds__(256) void k_prepA(const float* __restrict__ Wsrc,
                                               unsigned short* __restrict__ A) {
    __shared__ float lw[9216];
    int o = blockIdx.x, t = threadIdx.x;
    const float* src = Wsrc + (size_t)o * 9216; // per o: [j=c*9+tap][e]
    for (int lin = t; lin < 9216; lin += 256) lw[lin] = src[lin];
    __syncthreads();
    unsigned short* dst = A + (size_t)o * 16 * 576;
    for (int lin = t; lin < 9216; lin += 256) {
        int e = lin / 576, col = lin - e * 576;
        int tap = col >> 6, c = col & 63;
        dst[e * 576 + col] = f2bf(lw[(c * 9 + tap) * 16 + e]);
    }
}

// ---------- predictor conv1x1 + relu -> r1[b][e][p] f32 ----------
__global__ __launch_bounds__(256) void k_pred1(const float* __restrict__ x,
                                               const float* __restrict__ pw,
                                               const float* __restrict__ pb,
                                               float* __restrict__ r1) {
    __shared__ float lpw[1024];
    __shared__ float lpb[16];
    int t = threadIdx.x;
    for (int lin = t; lin < 1024; lin += 256) lpw[lin] = pw[lin];
    if (t < 16) lpb[t] = pb[t];
    __syncthreads();
    int gp = blockIdx.x * 256 + t;
    int b = gp >> 14, p = gp & 16383;
    const float* xs = x + (size_t)b * C_ * P_ + p;
    float s[16];
#pragma unroll
    for (int e = 0; e < 16; ++e) s[e] = lpb[e];
    for (int c = 0; c < 64; ++c) {
        float xv = xs[(size_t)c * P_];
#pragma unroll
        for (int e = 0; e < 16; ++e) s[e] = fmaf(lpw[e * 64 + c], xv, s[e]);
    }
    float* d = r1 + (size_t)b * 16 * P_ + p;
#pragma unroll
    for (int e = 0; e < 16; ++e) d[(size_t)e * P_] = fmaxf(s[e], 0.f);
}

// ---------- predictor conv3x3 -> para[b][e][p] f32 ----------
__global__ __launch_bounds__(256) void k_pred2(const float* __restrict__ r1,
                                               const float* __restrict__ cw,
                                               const float* __restrict__ cb,
                                               float* __restrict__ para) {
    __shared__ float lcw[2304];
    __shared__ float lcb[16];
    int t = threadIdx.x;
    for (int lin = t; lin < 2304; lin += 256) lcw[lin] = cw[lin];
    if (t < 16) lcb[t] = cb[t];
    __syncthreads();
    int gp = blockIdx.x * 256 + t;
    int b = gp >> 14, p = gp & 16383;
    int y = p >> 7, xc = p & 127;
    const float* rs = r1 + (size_t)b * 16 * P_;
    float s[16];
#pragma unroll
    for (int e = 0; e < 16; ++e) s[e] = lcb[e];
    for (int dy = 0; dy < 3; ++dy) {
        int yy = y + dy - 1;
        if (yy < 0 || yy > 127) continue;
        for (int dx = 0; dx < 3; ++dx) {
            int xv = xc + dx - 1;
            if (xv < 0 || xv > 127) continue;
            int q = yy * 128 + xv;
            int tap = dy * 3 + dx;
#pragma unroll
            for (int ep = 0; ep < 16; ++ep) {
                float v = rs[(size_t)ep * P_ + q];
#pragma unroll
                for (int e = 0; e < 16; ++e)
                    s[e] = fmaf(lcw[(e * 16 + ep) * 9 + tap], v, s[e]);
            }
        }
    }
    float* d = para + (size_t)b * 16 * P_ + p;
#pragma unroll
    for (int e = 0; e < 16; ++e) d[(size_t)e * P_] = s[e];
}

// ---------- main fused kernel ----------
// 512 threads (8 waves), 4 image rows x 16 o's (osl). Wave = (wrow, pxhalf):
// 4 o's x 64 px -> acc[4][4] = 64 AGPR (half of R6). 4 row-chunks of 4 o's;
// ALL waves share the chunk's A-stream (L1 broadcast). Freed registers fund a
// uniform 2-buffer af+bf prefetch chain: body t prefetches body t+1's
// fragments; kw statically unrolled (named qv scalars), kh runtime unroll-1.
__global__ __launch_bounds__(512, 2) void k_main(const unsigned short* __restrict__ xt,
                                                 const unsigned short* __restrict__ A,
                                                 const float* __restrict__ para,
                                                 float* __restrict__ out) {
    __shared__ unsigned short lds[6 * 130 * 64]; // 99,840 B
    int r = blockIdx.x;
    int xcd = r & 7;
    int ord = r >> 3;
    int osl = ord & 3;          // o-slice: 16 o's
    int bygl = ord >> 2;        // [0,16)
    int byg = bygl * 8 + xcd;   // [0,128)
    int b = byg >> 5, yg = byg & 31;
    int y0 = yg * 4;

    int tid = threadIdx.x;
    int wave = tid >> 6, lane = tid & 63, lhi = lane >> 4, llo = lane & 15;
    int wrow = wave & 3, pxh = wave >> 2;

    // stage 6 padded xt rows (y0..y0+5), swizzle byte ^= ((xx&7)<<4)
    const unsigned short* xrow = xt + (size_t)(b * 130 + y0) * 130 * 64;
    for (int ci = tid; ci < 6240; ci += 512) {
        int row = ci / 1040, rem = ci - row * 1040;
        int xx = rem >> 3, cc = rem & 7;
        short8 v = *(const short8*)(xrow + ((size_t)row * 130 + xx) * 64 + cc * 8);
        int lb = row * 16640 + xx * 128 + ((cc * 16) ^ ((xx & 7) << 4));
        *(short8*)((char*)lds + lb) = v;
    }
    __syncthreads();

    int y = y0 + wrow;
    const float* pp = para + (size_t)b * 16 * P_ + y * 128 + pxh * 64;
    float* po = out + (size_t)b * 64 * P_ + y * 128 + pxh * 64;

    // named LDS vaddrs q{par}{kw}; full addr = ldsc + kh*16640 + q
    int q00, q01, q02, q10, q11, q12;
    {
        int r0 = pxh * 64 + llo + 0;
        int r1i = pxh * 64 + llo + 1;
        int r2 = pxh * 64 + llo + 2;
        q00 = wrow * 16640 + r0 * 128 + ((lhi * 16) ^ ((r0 & 7) << 4));
        q01 = wrow * 16640 + r1i * 128 + ((lhi * 16) ^ ((r1i & 7) << 4));
        q02 = wrow * 16640 + r2 * 128 + ((lhi * 16) ^ ((r2 & 7) << 4));
        q10 = q00 ^ 64; q11 = q01 ^ 64; q12 = q02 ^ 64;
    }
    const char* ldsc = (const char*)lds;

#define PF_AF(dst, KOFF) do { \
    _Pragma("unroll") \
    for (int f_ = 0; f_ < 4; ++f_) \
        dst[f_] = *(const bf16x8*)(Abk + (size_t)f_ * 9216 + (KOFF)); \
} while (0)

#define PF_BF(dst, BADDR) do { \
    const char* bp_ = (BADDR); \
    _Pragma("unroll") \
    for (int pg_ = 0; pg_ < 4; ++pg_) \
        dst[pg_] = *(const bf16x8*)(bp_ + pg_ * 2048); \
} while (0)

#define MFMA16(afU, bfU) do { \
    __builtin_amdgcn_s_setprio(1); \
    _Pragma("unroll") \
    for (int f_ = 0; f_ < 4; ++f_) \
    _Pragma("unroll") \
    for (int pg_ = 0; pg_ < 4; ++pg_) \
        acc[f_][pg_] = __builtin_amdgcn_mfma_f32_16x16x32_bf16(afU[f_], bfU[pg_], acc[f_][pg_], 0, 0, 0); \
    __builtin_amdgcn_s_setprio(0); \
} while (0)

#pragma unroll 1
    for (int chunk = 0; chunk < 4; ++chunk) {
        int ob = osl * 16 + chunk * 4; // first o of this chunk (4 o's)
        const unsigned short* Ab = A + (size_t)(ob * 16 + llo) * 576 + lhi * 8;

        f32x4 acc[4][4];
#pragma unroll
        for (int f = 0; f < 4; ++f)
#pragma unroll
            for (int pg = 0; pg < 4; ++pg) acc[f][pg] = (f32x4){0.f, 0.f, 0.f, 0.f};

        bf16x8 afA[4], afB[4], bfA[4], bfB[4];
        // prologue: fragments for body 0 (kh=0,kw=0,par=0)
        {
            const unsigned short* Abk = Ab;
            PF_AF(afA, 0);
            PF_BF(bfA, ldsc + q00);
        }

#pragma unroll 1
        for (int kh = 0; kh < 3; ++kh) {
            const unsigned short* Abk = Ab + kh * 192; // elements; 6 ks * 32
            const char* bprow = ldsc + kh * 16640;
            // t0: use A, fill B with (kw0,par1)
            PF_AF(afB, 32);  PF_BF(bfB, bprow + q10);  MFMA16(afA, bfA);
            // t1: use B, fill A with (kw1,par0)
            PF_AF(afA, 64);  PF_BF(bfA, bprow + q01);  MFMA16(afB, bfB);
            // t2: use A, fill B with (kw1,par1)
            PF_AF(afB, 96);  PF_BF(bfB, bprow + q11);  MFMA16(afA, bfA);
            // t3: use B, fill A with (kw2,par0)
            PF_AF(afA, 128); PF_BF(bfA, bprow + q02);  MFMA16(afB, bfB);
            // t4: use A, fill B with (kw2,par1)
            PF_AF(afB, 160); PF_BF(bfB, bprow + q12);  MFMA16(afA, bfA);
            // t5: use B, fill A with next kh's (kw0,par0)
            if (kh < 2) {
                PF_AF(afA, 192);
                PF_BF(bfA, bprow + 16640 + q00);
            }
            MFMA16(afB, bfB);
        }

        // epilogue: multiply rows (e = lhi*4+rr) by para[e,p], reduce over e
        float pvv[4][4];
#pragma unroll
        for (int pg = 0; pg < 4; ++pg)
#pragma unroll
            for (int rr = 0; rr < 4; ++rr)
                pvv[pg][rr] = pp[(size_t)(lhi * 4 + rr) * P_ + pg * 16 + llo];

#pragma unroll
        for (int f = 0; f < 4; ++f) {
            int o = ob + f;
#pragma unroll
            for (int pg = 0; pg < 4; ++pg) {
                float s = acc[f][pg][0] * pvv[pg][0] + acc[f][pg][1] * pvv[pg][1] +
                          acc[f][pg][2] * pvv[pg][2] + acc[f][pg][3] * pvv[pg][3];
                s += __shfl_xor(s, 16);
                s += __shfl_xor(s, 32);
                if (lhi == 0)
                    __builtin_nontemporal_store(s, &po[(size_t)o * P_ + pg * 16 + llo]);
            }
        }
    }
#undef PF_AF
#undef PF_BF
#undef MFMA16
}

extern "C" void kernel_launch(void* const* d_in, const int* in_sizes, int n_in,
                              void* d_out, int out_size, void* d_ws, size_t ws_size,
                              hipStream_t stream) {
    const float* x  = (const float*)d_in[0];
    const float* W  = (const float*)d_in[1];
    const float* pw = (const float*)d_in[2];
    const float* pb = (const float*)d_in[3];
    const float* cw = (const float*)d_in[4];
    const float* cb = (const float*)d_in[5];
    float* out = (float*)d_out;
    char* ws = (char*)d_ws;
    unsigned short* xt = (unsigned short*)(ws + OFF_XT);
    unsigned short* Am = (unsigned short*)(ws + OFF_A);
    float* r1   = (float*)(ws + OFF_R1);
    float* para = (float*)(ws + OFF_PARA);

    hipLaunchKernelGGL(k_transpose, dim3(B_ * H_), dim3(128), 0, stream, x, xt);
    hipLaunchKernelGGL(k_prepA, dim3(64), dim3(256), 0, stream, W, Am);
    hipLaunchKernelGGL(k_pred1, dim3(B_ * P_ / 256), dim3(256), 0, stream, x, pw, pb, r1);
    hipLaunchKernelGGL(k_pred2, dim3(B_ * P_ / 256), dim3(256), 0, stream, r1, cw, cb, para);
    hipLaunchKernelGGL(k_main, dim3(512), dim3(512), 0, stream, xt, Am, para, out);
}

// Round 10
// 110.681 us; speedup vs baseline: 1.7067x; 1.7067x over previous
//
#include <hip/hip_runtime.h>

typedef __attribute__((ext_vector_type(8))) short short8;
typedef __attribute__((ext_vector_type(8))) __bf16 bf16x8;
typedef __attribute__((ext_vector_type(4))) float f32x4;

// sizes
#define B_ 4
#define C_ 64
#define H_ 128
#define W_ 128
#define P_ (H_*W_)      // 16384
#define E_ 16

// ws layout (bytes)
#define OFF_XT   0u
#define XT_BYTES (4u*130u*130u*64u*2u)          // 8,652,800
#define OFF_A    8652800u
#define OFF_R1   9832448u
#define OFF_PARA 14026752u

__device__ inline unsigned short f2bf(float f) {
    union { float f; unsigned u; } v; v.f = f;
    unsigned r = v.u + 0x7FFF + ((v.u >> 16) & 1);
    return (unsigned short)(r >> 16);
}

// ---------- transpose+pad x -> xt bf16, FUSED with conv1x1+relu -> r1 ----------
// Thread t (pixel) loads all 64 channels once: feeds both the bf16 transpose
// store and the 16-basis 1x1-conv accumulation (saves pred1's 16.7MB re-read).
__global__ __launch_bounds__(128) void k_transpose(const float* __restrict__ x,
                                                   unsigned short* __restrict__ xt,
                                                   const float* __restrict__ pw,
                                                   const float* __restrict__ pb,
                                                   float* __restrict__ r1) {
    __shared__ float lpw[1024];
    __shared__ float lpb[16];
    int b = blockIdx.x >> 7, y = blockIdx.x & 127;
    int t = threadIdx.x; // x coordinate
    for (int lin = t; lin < 1024; lin += 128) lpw[lin] = pw[lin];
    if (t < 16) lpb[t] = pb[t];
    __syncthreads();

    const float* src = x + (size_t)b * C_ * P_ + y * W_ + t;
    unsigned short* dst = xt + ((size_t)(b * 130 + y + 1) * 130 + t + 1) * 64;
    float s[16];
#pragma unroll
    for (int e = 0; e < 16; ++e) s[e] = lpb[e];
#pragma unroll
    for (int i = 0; i < 8; ++i) {
        short8 v;
#pragma unroll
        for (int j = 0; j < 8; ++j) {
            float xv = src[(size_t)(i * 8 + j) * P_];
            v[j] = (short)f2bf(xv);
#pragma unroll
            for (int e = 0; e < 16; ++e) s[e] = fmaf(lpw[e * 64 + i * 8 + j], xv, s[e]);
        }
        ((short8*)dst)[i] = v;
    }
    float* rd = r1 + (size_t)b * 16 * P_ + y * 128 + t;
#pragma unroll
    for (int e = 0; e < 16; ++e) rd[(size_t)e * P_] = fmaxf(s[e], 0.f);

    short8 z = {0,0,0,0,0,0,0,0};
    if (t < 16) {
        int col = (t >> 3) * 129, i = t & 7;
        unsigned short* bp = xt + ((size_t)(b * 130 + y + 1) * 130 + col) * 64;
        ((short8*)bp)[i] = z;
    }
    if (y == 0 || y == 127) {
        int prow = (y == 0) ? 0 : 129;
        unsigned short* rp = xt + (size_t)(b * 130 + prow) * 130 * 64;
        for (int ci = t; ci < 1040; ci += 128) ((short8*)rp)[ci] = z;
    }
}

// ---------- build A3 (fragment-linear) from W ----------
// A3 element offset = (g*72 + ks*4 + f)*512 + lane*8 + j   (g = o>>2, f = o&3)
// value = A_orig[row = o*16 + llo][col = ks*32 + lhi*8 + j], col = tap*64 + c
// (this exact layout+read-path passed validation in R4)
__global__ __launch_bounds__(256) void k_prepA(const float* __restrict__ Wsrc,
                                               unsigned short* __restrict__ A) {
    __shared__ float lw[9216];
    int o = blockIdx.x, t = threadIdx.x;
    const float* src = Wsrc + (size_t)o * 9216; // per o: [j'=c*9+tap][e]
    for (int lin = t; lin < 9216; lin += 256) lw[lin] = src[lin];
    __syncthreads();
    int g = o >> 2, f = o & 3;
    unsigned short* dst = A + ((size_t)g * 72 + f) * 512;
    for (int lin = t; lin < 9216; lin += 256) {
        int ks = lin >> 9, rem = lin & 511;
        int lane = rem >> 3, j = rem & 7;
        int llo = lane & 15, lhi = lane >> 4;
        int col = ks * 32 + lhi * 8 + j;
        int tap = col >> 6, c = col & 63;
        dst[(size_t)ks * 2048 + rem] = f2bf(lw[(c * 9 + tap) * 16 + llo]);
    }
}

// ---------- predictor conv3x3 -> para[b][e][p] f32 ----------
__global__ __launch_bounds__(256) void k_pred2(const float* __restrict__ r1,
                                               const float* __restrict__ cw,
                                               const float* __restrict__ cb,
                                               float* __restrict__ para) {
    __shared__ float lcw[2304];
    __shared__ float lcb[16];
    int t = threadIdx.x;
    for (int lin = t; lin < 2304; lin += 256) lcw[lin] = cw[lin];
    if (t < 16) lcb[t] = cb[t];
    __syncthreads();
    int gp = blockIdx.x * 256 + t;
    int b = gp >> 14, p = gp & 16383;
    int y = p >> 7, xc = p & 127;
    const float* rs = r1 + (size_t)b * 16 * P_;
    float s[16];
#pragma unroll
    for (int e = 0; e < 16; ++e) s[e] = lcb[e];
    for (int dy = 0; dy < 3; ++dy) {
        int yy = y + dy - 1;
        if (yy < 0 || yy > 127) continue;
        for (int dx = 0; dx < 3; ++dx) {
            int xv = xc + dx - 1;
            if (xv < 0 || xv > 127) continue;
            int q = yy * 128 + xv;
            int tap = dy * 3 + dx;
#pragma unroll
            for (int ep = 0; ep < 16; ++ep) {
                float v = rs[(size_t)ep * P_ + q];
#pragma unroll
                for (int e = 0; e < 16; ++e)
                    s[e] = fmaf(lcw[(e * 16 + ep) * 9 + tap], v, s[e]);
            }
        }
    }
    float* d = para + (size_t)b * 16 * P_ + p;
#pragma unroll
    for (int e = 0; e < 16; ++e) d[(size_t)e * P_] = s[e];
}

// ---------- main fused kernel ----------
// R6 skeleton (proven clean: VGPR 128, no spill): 512 threads (8 waves),
// 4 image rows x 16 o's, LDS 99,840 B, af 1-deep prefetch, setprio.
// R10 change: A read from fragment-linear A3 -> each af load is ONE coalesced
// 1KB wave transaction (was 16 scattered 64B segments, ~2000 cy/body of
// serialized memory-pipe service). sched_barrier(0) pins prefetch placement.
__global__ __launch_bounds__(512, 2) void k_main(const unsigned short* __restrict__ xt,
                                                 const unsigned short* __restrict__ A,
                                                 const float* __restrict__ para,
                                                 float* __restrict__ out) {
    __shared__ unsigned short lds[6 * 130 * 64]; // 99,840 B
    int r = blockIdx.x;
    int xcd = r & 7;
    int ord = r >> 3;
    int osl = ord & 3;          // o-slice: 16 o's
    int bygl = ord >> 2;        // [0,16)
    int byg = bygl * 8 + xcd;   // [0,128)
    int b = byg >> 5, yg = byg & 31;
    int y0 = yg * 4;            // first image row of this block

    int tid = threadIdx.x;
    int wave = tid >> 6, lane = tid & 63, lhi = lane >> 4, llo = lane & 15;
    int wrow = wave & 3, ohalf = wave >> 2;

    // stage 6 padded xt rows (y0..y0+5), swizzle byte ^= ((xx&7)<<4)
    const unsigned short* xrow = xt + (size_t)(b * 130 + y0) * 130 * 64;
    for (int ci = tid; ci < 6240; ci += 512) {
        int row = ci / 1040, rem = ci - row * 1040;
        int xx = rem >> 3, cc = rem & 7;
        short8 v = *(const short8*)(xrow + ((size_t)row * 130 + xx) * 64 + cc * 8);
        int lb = row * 16640 + xx * 128 + ((cc * 16) ^ ((xx & 7) << 4));
        *(short8*)((char*)lds + lb) = v;
    }
    __syncthreads();

    int y = y0 + wrow;
    const float* pp = para + (size_t)b * 16 * P_ + y * 128;
    float* po = out + (size_t)b * 64 * P_ + y * 128;

    // precomputed LDS read vaddrs: qv[parity][kw]; full addr = qv + kh*16640 + pg*2048
    int qv[2][3];
#pragma unroll
    for (int kw = 0; kw < 3; ++kw) {
        int rowi = llo + kw;
        int base0 = wrow * 16640 + rowi * 128 + ((lhi * 16) ^ ((rowi & 7) << 4));
        qv[0][kw] = base0;
        qv[1][kw] = base0 ^ 64;
    }
    const char* ldsc = (const char*)lds;

#define PF_AF(dst, KS) do { \
    _Pragma("unroll") \
    for (int f_ = 0; f_ < 4; ++f_) \
        dst[f_] = *(const bf16x8*)(Agl + (KS) * 2048 + f_ * 512); \
    __builtin_amdgcn_sched_barrier(0); \
} while (0)

#pragma unroll 1
    for (int chunk = 0; chunk < 2; ++chunk) {
        int obase = osl * 16 + ohalf * 8 + chunk * 4;
        int g = obase >> 2; // o-group index into A3
        const unsigned short* Agl = A + (size_t)g * 36864 + lane * 8;

        f32x4 acc[4][8];
#pragma unroll
        for (int f = 0; f < 4; ++f)
#pragma unroll
            for (int pg = 0; pg < 8; ++pg) acc[f][pg] = (f32x4){0.f, 0.f, 0.f, 0.f};

        bf16x8 afA[4], afB[4];
        // prologue: A-frags for ks=0
        PF_AF(afA, 0);

#pragma unroll 1
        for (int kh = 0; kh < 3; ++kh) {
#pragma unroll 1
            for (int kw = 0; kw < 3; ++kw) {
                const int ksc = kh * 6 + kw * 2; // current even ks
                const char* bprow = ldsc + kh * 16640;
                // ---- half 0 (parity 0): compute with afA, prefetch ksc+1 -> afB
                {
                    PF_AF(afB, ksc + 1);
                    const char* bp = bprow + qv[0][kw];
                    bf16x8 bf[8];
#pragma unroll
                    for (int pg = 0; pg < 8; ++pg)
                        bf[pg] = *(const bf16x8*)(bp + pg * 2048);
                    __builtin_amdgcn_s_setprio(1);
#pragma unroll
                    for (int f = 0; f < 4; ++f)
#pragma unroll
                        for (int pg = 0; pg < 8; ++pg)
                            acc[f][pg] = __builtin_amdgcn_mfma_f32_16x16x32_bf16(afA[f], bf[pg], acc[f][pg], 0, 0, 0);
                    __builtin_amdgcn_s_setprio(0);
                }
                // ---- half 1 (parity 1): compute with afB, prefetch ksc+2 -> afA
                {
                    // ksc+2==18 at the very end reads past this g's A3 slice
                    // (into g+1 / ws scratch) -- prefetched but never consumed.
                    PF_AF(afA, ksc + 2);
                    const char* bp = bprow + qv[1][kw];
                    bf16x8 bf[8];
#pragma unroll
                    for (int pg = 0; pg < 8; ++pg)
                        bf[pg] = *(const bf16x8*)(bp + pg * 2048);
                    __builtin_amdgcn_s_setprio(1);
#pragma unroll
                    for (int f = 0; f < 4; ++f)
#pragma unroll
                        for (int pg = 0; pg < 8; ++pg)
                            acc[f][pg] = __builtin_amdgcn_mfma_f32_16x16x32_bf16(afB[f], bf[pg], acc[f][pg], 0, 0, 0);
                    __builtin_amdgcn_s_setprio(0);
                }
            }
        }

        // epilogue: multiply rows (e) by para[e,p], reduce over e
        float pvv[8][4];
#pragma unroll
        for (int pg = 0; pg < 8; ++pg)
#pragma unroll
            for (int rr = 0; rr < 4; ++rr)
                pvv[pg][rr] = pp[(size_t)(lhi * 4 + rr) * P_ + pg * 16 + llo];

#pragma unroll
        for (int f = 0; f < 4; ++f) {
            int o = obase + f;
#pragma unroll
            for (int pg = 0; pg < 8; ++pg) {
                float s = acc[f][pg][0] * pvv[pg][0] + acc[f][pg][1] * pvv[pg][1] +
                          acc[f][pg][2] * pvv[pg][2] + acc[f][pg][3] * pvv[pg][3];
                s += __shfl_xor(s, 16);
                s += __shfl_xor(s, 32);
                if (lhi == 0)
                    __builtin_nontemporal_store(s, &po[(size_t)o * P_ + pg * 16 + llo]);
            }
        }
    }
#undef PF_AF
}

extern "C" void kernel_launch(void* const* d_in, const int* in_sizes, int n_in,
                              void* d_out, int out_size, void* d_ws, size_t ws_size,
                              hipStream_t stream) {
    const float* x  = (const float*)d_in[0];
    const float* W  = (const float*)d_in[1];
    const float* pw = (const float*)d_in[2];
    const float* pb = (const float*)d_in[3];
    const float* cw = (const float*)d_in[4];
    const float* cb = (const float*)d_in[5];
    float* out = (float*)d_out;
    char* ws = (char*)d_ws;
    unsigned short* xt = (unsigned short*)(ws + OFF_XT);
    unsigned short* Am = (unsigned short*)(ws + OFF_A);
    float* r1   = (float*)(ws + OFF_R1);
    float* para = (float*)(ws + OFF_PARA);

    hipLaunchKernelGGL(k_transpose, dim3(B_ * H_), dim3(128), 0, stream, x, xt, pw, pb, r1);
    hipLaunchKernelGGL(k_prepA, dim3(64), dim3(256), 0, stream, W, Am);
    hipLaunchKernelGGL(k_pred2, dim3(B_ * P_ / 256), dim3(256), 0, stream, r1, cw, cb, para);
    hipLaunchKernelGGL(k_main, dim3(512), dim3(512), 0, stream, xt, Am, para, out);
}

// Round 11
// 109.182 us; speedup vs baseline: 1.7302x; 1.0137x over previous
//
#include <hip/hip_runtime.h>

typedef __attribute__((ext_vector_type(8))) short short8;
typedef __attribute__((ext_vector_type(8))) __bf16 bf16x8;
typedef __attribute__((ext_vector_type(4))) float f32x4;

// sizes
#define B_ 4
#define C_ 64
#define H_ 128
#define W_ 128
#define P_ (H_*W_)      // 16384
#define E_ 16

// ws layout (bytes)
#define OFF_XT   0u
#define XT_BYTES (4u*130u*130u*64u*2u)          // 8,652,800
#define OFF_A    8652800u
#define OFF_R1   9832448u
#define OFF_PARA 14026752u

__device__ inline unsigned short f2bf(float f) {
    union { float f; unsigned u; } v; v.f = f;
    unsigned r = v.u + 0x7FFF + ((v.u >> 16) & 1);
    return (unsigned short)(r >> 16);
}

// ---------- transpose+pad x -> xt bf16, FUSED with conv1x1+relu -> r1 ----------
__global__ __launch_bounds__(128) void k_transpose(const float* __restrict__ x,
                                                   unsigned short* __restrict__ xt,
                                                   const float* __restrict__ pw,
                                                   const float* __restrict__ pb,
                                                   float* __restrict__ r1) {
    __shared__ float lpw[1024];
    __shared__ float lpb[16];
    int b = blockIdx.x >> 7, y = blockIdx.x & 127;
    int t = threadIdx.x; // x coordinate
    for (int lin = t; lin < 1024; lin += 128) lpw[lin] = pw[lin];
    if (t < 16) lpb[t] = pb[t];
    __syncthreads();

    const float* src = x + (size_t)b * C_ * P_ + y * W_ + t;
    unsigned short* dst = xt + ((size_t)(b * 130 + y + 1) * 130 + t + 1) * 64;
    float s[16];
#pragma unroll
    for (int e = 0; e < 16; ++e) s[e] = lpb[e];
#pragma unroll
    for (int i = 0; i < 8; ++i) {
        short8 v;
#pragma unroll
        for (int j = 0; j < 8; ++j) {
            float xv = src[(size_t)(i * 8 + j) * P_];
            v[j] = (short)f2bf(xv);
#pragma unroll
            for (int e = 0; e < 16; ++e) s[e] = fmaf(lpw[e * 64 + i * 8 + j], xv, s[e]);
        }
        ((short8*)dst)[i] = v;
    }
    float* rd = r1 + (size_t)b * 16 * P_ + y * 128 + t;
#pragma unroll
    for (int e = 0; e < 16; ++e) rd[(size_t)e * P_] = fmaxf(s[e], 0.f);

    short8 z = {0,0,0,0,0,0,0,0};
    if (t < 16) {
        int col = (t >> 3) * 129, i = t & 7;
        unsigned short* bp = xt + ((size_t)(b * 130 + y + 1) * 130 + col) * 64;
        ((short8*)bp)[i] = z;
    }
    if (y == 0 || y == 127) {
        int prow = (y == 0) ? 0 : 129;
        unsigned short* rp = xt + (size_t)(b * 130 + prow) * 130 * 64;
        for (int ci = t; ci < 1040; ci += 128) ((short8*)rp)[ci] = z;
    }
}

// ---------- build A3 (fragment-linear) from W ----------
// A3 element offset = (g*72 + ks*4 + f)*512 + lane*8 + j   (g = o>>2, f = o&3)
// value = A_orig[row = o*16 + llo][col = ks*32 + lhi*8 + j], col = tap*64 + c
__global__ __launch_bounds__(256) void k_prepA(const float* __restrict__ Wsrc,
                                               unsigned short* __restrict__ A) {
    __shared__ float lw[9216];
    int o = blockIdx.x, t = threadIdx.x;
    const float* src = Wsrc + (size_t)o * 9216; // per o: [j'=c*9+tap][e]
    for (int lin = t; lin < 9216; lin += 256) lw[lin] = src[lin];
    __syncthreads();
    int g = o >> 2, f = o & 3;
    unsigned short* dst = A + ((size_t)g * 72 + f) * 512;
    for (int lin = t; lin < 9216; lin += 256) {
        int ks = lin >> 9, rem = lin & 511;
        int lane = rem >> 3, j = rem & 7;
        int llo = lane & 15, lhi = lane >> 4;
        int col = ks * 32 + lhi * 8 + j;
        int tap = col >> 6, c = col & 63;
        dst[(size_t)ks * 2048 + rem] = f2bf(lw[(c * 9 + tap) * 16 + llo]);
    }
}

// ---------- predictor conv3x3 -> para[b][e][p] f32 ----------
__global__ __launch_bounds__(256) void k_pred2(const float* __restrict__ r1,
                                               const float* __restrict__ cw,
                                               const float* __restrict__ cb,
                                               float* __restrict__ para) {
    __shared__ float lcw[2304];
    __shared__ float lcb[16];
    int t = threadIdx.x;
    for (int lin = t; lin < 2304; lin += 256) lcw[lin] = cw[lin];
    if (t < 16) lcb[t] = cb[t];
    __syncthreads();
    int gp = blockIdx.x * 256 + t;
    int b = gp >> 14, p = gp & 16383;
    int y = p >> 7, xc = p & 127;
    const float* rs = r1 + (size_t)b * 16 * P_;
    float s[16];
#pragma unroll
    for (int e = 0; e < 16; ++e) s[e] = lcb[e];
    for (int dy = 0; dy < 3; ++dy) {
        int yy = y + dy - 1;
        if (yy < 0 || yy > 127) continue;
        for (int dx = 0; dx < 3; ++dx) {
            int xv = xc + dx - 1;
            if (xv < 0 || xv > 127) continue;
            int q = yy * 128 + xv;
            int tap = dy * 3 + dx;
#pragma unroll
            for (int ep = 0; ep < 16; ++ep) {
                float v = rs[(size_t)ep * P_ + q];
#pragma unroll
                for (int e = 0; e < 16; ++e)
                    s[e] = fmaf(lcw[(e * 16 + ep) * 9 + tap], v, s[e]);
            }
        }
    }
    float* d = para + (size_t)b * 16 * P_ + p;
#pragma unroll
    for (int e = 0; e < 16; ++e) d[(size_t)e * P_] = s[e];
}

// ---------- main fused kernel ----------
// R10 skeleton (fragment-linear A, VGPR-clean) + R11 change: per-body bf reads
// software-pipelined at FRAGMENT granularity -- 8 clusters of
// {1 ds_read (frag j+2, 4-buffer rotation B0..B3) -> 4 MFMA on frag j},
// sched_barrier(0)-pinned. LDS port streams under the MFMA stream instead of
// alternating with it (the measured 770cy LDS + 1030cy MFMA serial pattern).
__global__ __launch_bounds__(512, 2) void k_main(const unsigned short* __restrict__ xt,
                                                 const unsigned short* __restrict__ A,
                                                 const float* __restrict__ para,
                                                 float* __restrict__ out) {
    __shared__ unsigned short lds[6 * 130 * 64]; // 99,840 B
    int r = blockIdx.x;
    int xcd = r & 7;
    int ord = r >> 3;
    int osl = ord & 3;          // o-slice: 16 o's
    int bygl = ord >> 2;        // [0,16)
    int byg = bygl * 8 + xcd;   // [0,128)
    int b = byg >> 5, yg = byg & 31;
    int y0 = yg * 4;            // first image row of this block

    int tid = threadIdx.x;
    int wave = tid >> 6, lane = tid & 63, lhi = lane >> 4, llo = lane & 15;
    int wrow = wave & 3, ohalf = wave >> 2;

    // stage 6 padded xt rows (y0..y0+5), swizzle byte ^= ((xx&7)<<4)
    const unsigned short* xrow = xt + (size_t)(b * 130 + y0) * 130 * 64;
    for (int ci = tid; ci < 6240; ci += 512) {
        int row = ci / 1040, rem = ci - row * 1040;
        int xx = rem >> 3, cc = rem & 7;
        short8 v = *(const short8*)(xrow + ((size_t)row * 130 + xx) * 64 + cc * 8);
        int lb = row * 16640 + xx * 128 + ((cc * 16) ^ ((xx & 7) << 4));
        *(short8*)((char*)lds + lb) = v;
    }
    __syncthreads();

    int y = y0 + wrow;
    const float* pp = para + (size_t)b * 16 * P_ + y * 128;
    float* po = out + (size_t)b * 64 * P_ + y * 128;

    // precomputed LDS read vaddrs: qv[parity][kw]; full addr = qv + kh*16640 + pg*2048
    int qv[2][3];
#pragma unroll
    for (int kw = 0; kw < 3; ++kw) {
        int rowi = llo + kw;
        int base0 = wrow * 16640 + rowi * 128 + ((lhi * 16) ^ ((rowi & 7) << 4));
        qv[0][kw] = base0;
        qv[1][kw] = base0 ^ 64;
    }
    const char* ldsc = (const char*)lds;

#define BF_ADDR(KS, PG) (ldsc + ((KS) / 6) * 16640 + qv[(KS) & 1][((KS) % 6) >> 1] + (PG) * 2048)

#define PF_AF(dst, KS) do { \
    if ((KS) < 18) { \
        _Pragma("unroll") \
        for (int f_ = 0; f_ < 4; ++f_) \
            dst[f_] = *(const bf16x8*)(Agl + (KS) * 2048 + f_ * 512); \
    } \
    __builtin_amdgcn_sched_barrier(0); \
} while (0)

// one cluster: prefetch frag (PFKS,PFPG) into PFBUF, then 4 MFMA on USEBUF
#define CL(PFBUF, PFKS, PFPG, USEBUF, USEPG, AFU) do { \
    if ((PFKS) < 18) PFBUF = *(const bf16x8*)BF_ADDR(PFKS, PFPG); \
    _Pragma("unroll") \
    for (int f_ = 0; f_ < 4; ++f_) \
        acc[f_][USEPG] = __builtin_amdgcn_mfma_f32_16x16x32_bf16(AFU[f_], USEBUF, acc[f_][USEPG], 0, 0, 0); \
    __builtin_amdgcn_sched_barrier(0); \
} while (0)

#define BODY(KS, AFU, AFP) do { \
    PF_AF(AFP, (KS) + 1); \
    __builtin_amdgcn_s_setprio(1); \
    CL(B2, (KS), 2, B0, 0, AFU);      CL(B3, (KS), 3, B1, 1, AFU); \
    CL(B0, (KS), 4, B2, 2, AFU);      CL(B1, (KS), 5, B3, 3, AFU); \
    CL(B2, (KS), 6, B0, 4, AFU);      CL(B3, (KS), 7, B1, 5, AFU); \
    CL(B0, (KS) + 1, 0, B2, 6, AFU);  CL(B1, (KS) + 1, 1, B3, 7, AFU); \
    __builtin_amdgcn_s_setprio(0); \
} while (0)

#pragma unroll 1
    for (int chunk = 0; chunk < 2; ++chunk) {
        int obase = osl * 16 + ohalf * 8 + chunk * 4;
        int g = obase >> 2; // o-group index into A3
        const unsigned short* Agl = A + (size_t)g * 36864 + lane * 8;

        f32x4 acc[4][8];
#pragma unroll
        for (int f = 0; f < 4; ++f)
#pragma unroll
            for (int pg = 0; pg < 8; ++pg) acc[f][pg] = (f32x4){0.f, 0.f, 0.f, 0.f};

        bf16x8 afA[4], afB[4], B0, B1, B2, B3;
        // prologue: af for body 0, first two bf frags
        PF_AF(afA, 0);
        B0 = *(const bf16x8*)BF_ADDR(0, 0);
        B1 = *(const bf16x8*)BF_ADDR(0, 1);

        BODY(0, afA, afB);  BODY(1, afB, afA);  BODY(2, afA, afB);
        BODY(3, afB, afA);  BODY(4, afA, afB);  BODY(5, afB, afA);
        BODY(6, afA, afB);  BODY(7, afB, afA);  BODY(8, afA, afB);
        BODY(9, afB, afA);  BODY(10, afA, afB); BODY(11, afB, afA);
        BODY(12, afA, afB); BODY(13, afB, afA); BODY(14, afA, afB);
        BODY(15, afB, afA); BODY(16, afA, afB); BODY(17, afB, afA);

        // epilogue: multiply rows (e) by para[e,p], reduce over e
        float pvv[8][4];
#pragma unroll
        for (int pg = 0; pg < 8; ++pg)
#pragma unroll
            for (int rr = 0; rr < 4; ++rr)
                pvv[pg][rr] = pp[(size_t)(lhi * 4 + rr) * P_ + pg * 16 + llo];

#pragma unroll
        for (int f = 0; f < 4; ++f) {
            int o = obase + f;
#pragma unroll
            for (int pg = 0; pg < 8; ++pg) {
                float s = acc[f][pg][0] * pvv[pg][0] + acc[f][pg][1] * pvv[pg][1] +
                          acc[f][pg][2] * pvv[pg][2] + acc[f][pg][3] * pvv[pg][3];
                s += __shfl_xor(s, 16);
                s += __shfl_xor(s, 32);
                if (lhi == 0)
                    __builtin_nontemporal_store(s, &po[(size_t)o * P_ + pg * 16 + llo]);
            }
        }
    }
#undef BF_ADDR
#undef PF_AF
#undef CL
#undef BODY
}

extern "C" void kernel_launch(void* const* d_in, const int* in_sizes, int n_in,
                              void* d_out, int out_size, void* d_ws, size_t ws_size,
                              hipStream_t stream) {
    const float* x  = (const float*)d_in[0];
    const float* W  = (const float*)d_in[1];
    const float* pw = (const float*)d_in[2];
    const float* pb = (const float*)d_in[3];
    const float* cw = (const float*)d_in[4];
    const float* cb = (const float*)d_in[5];
    float* out = (float*)d_out;
    char* ws = (char*)d_ws;
    unsigned short* xt = (unsigned short*)(ws + OFF_XT);
    unsigned short* Am = (unsigned short*)(ws + OFF_A);
    float* r1   = (float*)(ws + OFF_R1);
    float* para = (float*)(ws + OFF_PARA);

    hipLaunchKernelGGL(k_transpose, dim3(B_ * H_), dim3(128), 0, stream, x, xt, pw, pb, r1);
    hipLaunchKernelGGL(k_prepA, dim3(64), dim3(256), 0, stream, W, Am);
    hipLaunchKernelGGL(k_pred2, dim3(B_ * P_ / 256), dim3(256), 0, stream, r1, cw, cb, para);
    hipLaunchKernelGGL(k_main, dim3(512), dim3(512), 0, stream, xt, Am, para, out);
}

// Round 12
// 108.535 us; speedup vs baseline: 1.7405x; 1.0060x over previous
//
#include <hip/hip_runtime.h>

typedef __attribute__((ext_vector_type(8))) short short8;
typedef __attribute__((ext_vector_type(8))) __bf16 bf16x8;
typedef __attribute__((ext_vector_type(4))) float f32x4;

// sizes
#define B_ 4
#define C_ 64
#define H_ 128
#define W_ 128
#define P_ (H_*W_)      // 16384
#define E_ 16

// ws layout (bytes)
#define OFF_XT   0u
#define XT_BYTES (4u*130u*130u*64u*2u)          // 8,652,800
#define OFF_A    8652800u
#define OFF_R1   9832448u
#define OFF_PARA 14026752u

__device__ inline unsigned short f2bf(float f) {
    union { float f; unsigned u; } v; v.f = f;
    unsigned r = v.u + 0x7FFF + ((v.u >> 16) & 1);
    return (unsigned short)(r >> 16);
}

// ---------- transpose+pad x -> xt bf16, FUSED with conv1x1+relu -> r1 ----------
__global__ __launch_bounds__(128) void k_transpose(const float* __restrict__ x,
                                                   unsigned short* __restrict__ xt,
                                                   const float* __restrict__ pw,
                                                   const float* __restrict__ pb,
                                                   float* __restrict__ r1) {
    __shared__ float lpw[1024];
    __shared__ float lpb[16];
    int b = blockIdx.x >> 7, y = blockIdx.x & 127;
    int t = threadIdx.x; // x coordinate
    for (int lin = t; lin < 1024; lin += 128) lpw[lin] = pw[lin];
    if (t < 16) lpb[t] = pb[t];
    __syncthreads();

    const float* src = x + (size_t)b * C_ * P_ + y * W_ + t;
    unsigned short* dst = xt + ((size_t)(b * 130 + y + 1) * 130 + t + 1) * 64;
    float s[16];
#pragma unroll
    for (int e = 0; e < 16; ++e) s[e] = lpb[e];
#pragma unroll
    for (int i = 0; i < 8; ++i) {
        short8 v;
#pragma unroll
        for (int j = 0; j < 8; ++j) {
            float xv = src[(size_t)(i * 8 + j) * P_];
            v[j] = (short)f2bf(xv);
#pragma unroll
            for (int e = 0; e < 16; ++e) s[e] = fmaf(lpw[e * 64 + i * 8 + j], xv, s[e]);
        }
        ((short8*)dst)[i] = v;
    }
    float* rd = r1 + (size_t)b * 16 * P_ + y * 128 + t;
#pragma unroll
    for (int e = 0; e < 16; ++e) rd[(size_t)e * P_] = fmaxf(s[e], 0.f);

    short8 z = {0,0,0,0,0,0,0,0};
    if (t < 16) {
        int col = (t >> 3) * 129, i = t & 7;
        unsigned short* bp = xt + ((size_t)(b * 130 + y + 1) * 130 + col) * 64;
        ((short8*)bp)[i] = z;
    }
    if (y == 0 || y == 127) {
        int prow = (y == 0) ? 0 : 129;
        unsigned short* rp = xt + (size_t)(b * 130 + prow) * 130 * 64;
        for (int ci = t; ci < 1040; ci += 128) ((short8*)rp)[ci] = z;
    }
}

// ---------- build A3 (fragment-linear) from W ----------
// A3 element offset = (g*72 + ks*4 + f)*512 + lane*8 + j   (g = o>>2, f = o&3)
// value = A_orig[row = o*16 + llo][col = ks*32 + lhi*8 + j], col = tap*64 + c
__global__ __launch_bounds__(256) void k_prepA(const float* __restrict__ Wsrc,
                                               unsigned short* __restrict__ A) {
    __shared__ float lw[9216];
    int o = blockIdx.x, t = threadIdx.x;
    const float* src = Wsrc + (size_t)o * 9216; // per o: [j'=c*9+tap][e]
    for (int lin = t; lin < 9216; lin += 256) lw[lin] = src[lin];
    __syncthreads();
    int g = o >> 2, f = o & 3;
    unsigned short* dst = A + ((size_t)g * 72 + f) * 512;
    for (int lin = t; lin < 9216; lin += 256) {
        int ks = lin >> 9, rem = lin & 511;
        int lane = rem >> 3, j = rem & 7;
        int llo = lane & 15, lhi = lane >> 4;
        int col = ks * 32 + lhi * 8 + j;
        int tap = col >> 6, c = col & 63;
        dst[(size_t)ks * 2048 + rem] = f2bf(lw[(c * 9 + tap) * 16 + llo]);
    }
}

// ---------- predictor conv3x3 -> para[b][e][p] f32 ----------
__global__ __launch_bounds__(256) void k_pred2(const float* __restrict__ r1,
                                               const float* __restrict__ cw,
                                               const float* __restrict__ cb,
                                               float* __restrict__ para) {
    __shared__ float lcw[2304];
    __shared__ float lcb[16];
    int t = threadIdx.x;
    for (int lin = t; lin < 2304; lin += 256) lcw[lin] = cw[lin];
    if (t < 16) lcb[t] = cb[t];
    __syncthreads();
    int gp = blockIdx.x * 256 + t;
    int b = gp >> 14, p = gp & 16383;
    int y = p >> 7, xc = p & 127;
    const float* rs = r1 + (size_t)b * 16 * P_;
    float s[16];
#pragma unroll
    for (int e = 0; e < 16; ++e) s[e] = lcb[e];
    for (int dy = 0; dy < 3; ++dy) {
        int yy = y + dy - 1;
        if (yy < 0 || yy > 127) continue;
        for (int dx = 0; dx < 3; ++dx) {
            int xv = xc + dx - 1;
            if (xv < 0 || xv > 127) continue;
            int q = yy * 128 + xv;
            int tap = dy * 3 + dx;
#pragma unroll
            for (int ep = 0; ep < 16; ++ep) {
                float v = rs[(size_t)ep * P_ + q];
#pragma unroll
                for (int e = 0; e < 16; ++e)
                    s[e] = fmaf(lcw[(e * 16 + ep) * 9 + tap], v, s[e]);
            }
        }
    }
    float* d = para + (size_t)b * 16 * P_ + p;
#pragma unroll
    for (int e = 0; e < 16; ++e) d[(size_t)e * P_] = s[e];
}

// ---------- main fused kernel ----------
// R12: R2 geometry (256 threads / 4 waves, ONE image row, 3 staged xt rows =
// 49,920 B LDS) x R10 per-wave loop (fragment-linear A3 af double-buffer,
// acc[4][8], setprio). 49.9KB LDS + ~128 VGPR -> up to 3 independent blocks/CU
// (3 waves/SIMD at DIFFERENT phases): block-level desync covers the per-wave
// serial stalls + staging/epilogue bubbles that lockstep same-block waves
// could not. Each block computes all 64 o's (4 chunks x 4 waves x 4 f).
__global__ __launch_bounds__(256, 2) void k_main(const unsigned short* __restrict__ xt,
                                                 const unsigned short* __restrict__ A,
                                                 const float* __restrict__ para,
                                                 float* __restrict__ out) {
    __shared__ unsigned short lds[3 * 130 * 64]; // 49,920 B
    int r = blockIdx.x;
    int xcd = r & 7;
    int yl = r >> 3;            // [0,64)
    int rowid = xcd * 64 + yl;  // contiguous 64-row slab per XCD (A stays L2-resident)
    int b = rowid >> 7, y = rowid & 127;

    int tid = threadIdx.x;
    int wave = tid >> 6, lane = tid & 63, lhi = lane >> 4, llo = lane & 15;

    // stage 3 padded xt rows (y..y+2), swizzle byte ^= ((xx&7)<<4)
    const unsigned short* xrow = xt + (size_t)(b * 130 + y) * 130 * 64;
    for (int ci = tid; ci < 3120; ci += 256) {
        int row = ci / 1040, rem = ci - row * 1040;
        int xx = rem >> 3, cc = rem & 7;
        short8 v = *(const short8*)(xrow + ((size_t)row * 130 + xx) * 64 + cc * 8);
        int lb = row * 16640 + xx * 128 + ((cc * 16) ^ ((xx & 7) << 4));
        *(short8*)((char*)lds + lb) = v;
    }
    __syncthreads();

    const float* pp = para + (size_t)b * 16 * P_ + y * 128;
    float* po = out + (size_t)b * 64 * P_ + y * 128;

    // precomputed LDS read vaddrs: qv[parity][kw]; full addr = qv + kh*16640 + pg*2048
    int qv[2][3];
#pragma unroll
    for (int kw = 0; kw < 3; ++kw) {
        int rowi = llo + kw;
        int base0 = rowi * 128 + ((lhi * 16) ^ ((rowi & 7) << 4));
        qv[0][kw] = base0;
        qv[1][kw] = base0 ^ 64;
    }
    const char* ldsc = (const char*)lds;

#define PF_AF(dst, KS) do { \
    _Pragma("unroll") \
    for (int f_ = 0; f_ < 4; ++f_) \
        dst[f_] = *(const bf16x8*)(Agl + (KS) * 2048 + f_ * 512); \
    __builtin_amdgcn_sched_barrier(0); \
} while (0)

#pragma unroll 1
    for (int chunk = 0; chunk < 4; ++chunk) {
        int obase = chunk * 16 + wave * 4;
        int g = obase >> 2; // o-group index into A3 (= chunk*4 + wave)
        const unsigned short* Agl = A + (size_t)g * 36864 + lane * 8;

        f32x4 acc[4][8];
#pragma unroll
        for (int f = 0; f < 4; ++f)
#pragma unroll
            for (int pg = 0; pg < 8; ++pg) acc[f][pg] = (f32x4){0.f, 0.f, 0.f, 0.f};

        bf16x8 afA[4], afB[4];
        // prologue: A-frags for ks=0
        PF_AF(afA, 0);

#pragma unroll 1
        for (int kh = 0; kh < 3; ++kh) {
#pragma unroll 1
            for (int kw = 0; kw < 3; ++kw) {
                const int ksc = kh * 6 + kw * 2; // current even ks
                const char* bprow = ldsc + kh * 16640;
                // ---- half 0 (parity 0): compute with afA, prefetch ksc+1 -> afB
                {
                    PF_AF(afB, ksc + 1);
                    const char* bp = bprow + qv[0][kw];
                    bf16x8 bf[8];
#pragma unroll
                    for (int pg = 0; pg < 8; ++pg)
                        bf[pg] = *(const bf16x8*)(bp + pg * 2048);
                    __builtin_amdgcn_s_setprio(1);
#pragma unroll
                    for (int f = 0; f < 4; ++f)
#pragma unroll
                        for (int pg = 0; pg < 8; ++pg)
                            acc[f][pg] = __builtin_amdgcn_mfma_f32_16x16x32_bf16(afA[f], bf[pg], acc[f][pg], 0, 0, 0);
                    __builtin_amdgcn_s_setprio(0);
                }
                // ---- half 1 (parity 1): compute with afB, prefetch ksc+2 -> afA
                {
                    // ksc+2==18 at the end reads 4KB past this g's slice (into
                    // the next slice / r1 region) -- prefetched, never consumed.
                    PF_AF(afA, ksc + 2);
                    const char* bp = bprow + qv[1][kw];
                    bf16x8 bf[8];
#pragma unroll
                    for (int pg = 0; pg < 8; ++pg)
                        bf[pg] = *(const bf16x8*)(bp + pg * 2048);
                    __builtin_amdgcn_s_setprio(1);
#pragma unroll
                    for (int f = 0; f < 4; ++f)
#pragma unroll
                        for (int pg = 0; pg < 8; ++pg)
                            acc[f][pg] = __builtin_amdgcn_mfma_f32_16x16x32_bf16(afB[f], bf[pg], acc[f][pg], 0, 0, 0);
                    __builtin_amdgcn_s_setprio(0);
                }
            }
        }

        // epilogue: multiply rows (e) by para[e,p], reduce over e
        float pvv[8][4];
#pragma unroll
        for (int pg = 0; pg < 8; ++pg)
#pragma unroll
            for (int rr = 0; rr < 4; ++rr)
                pvv[pg][rr] = pp[(size_t)(lhi * 4 + rr) * P_ + pg * 16 + llo];

#pragma unroll
        for (int f = 0; f < 4; ++f) {
            int o = obase + f;
#pragma unroll
            for (int pg = 0; pg < 8; ++pg) {
                float s = acc[f][pg][0] * pvv[pg][0] + acc[f][pg][1] * pvv[pg][1] +
                          acc[f][pg][2] * pvv[pg][2] + acc[f][pg][3] * pvv[pg][3];
                s += __shfl_xor(s, 16);
                s += __shfl_xor(s, 32);
                if (lhi == 0)
                    __builtin_nontemporal_store(s, &po[(size_t)o * P_ + pg * 16 + llo]);
            }
        }
    }
#undef PF_AF
}

extern "C" void kernel_launch(void* const* d_in, const int* in_sizes, int n_in,
                              void* d_out, int out_size, void* d_ws, size_t ws_size,
                              hipStream_t stream) {
    const float* x  = (const float*)d_in[0];
    const float* W  = (const float*)d_in[1];
    const float* pw = (const float*)d_in[2];
    const float* pb = (const float*)d_in[3];
    const float* cw = (const float*)d_in[4];
    const float* cb = (const float*)d_in[5];
    float* out = (float*)d_out;
    char* ws = (char*)d_ws;
    unsigned short* xt = (unsigned short*)(ws + OFF_XT);
    unsigned short* Am = (unsigned short*)(ws + OFF_A);
    float* r1   = (float*)(ws + OFF_R1);
    float* para = (float*)(ws + OFF_PARA);

    hipLaunchKernelGGL(k_transpose, dim3(B_ * H_), dim3(128), 0, stream, x, xt, pw, pb, r1);
    hipLaunchKernelGGL(k_prepA, dim3(64), dim3(256), 0, stream, W, Am);
    hipLaunchKernelGGL(k_pred2, dim3(B_ * P_ / 256), dim3(256), 0, stream, r1, cw, cb, para);
    hipLaunchKernelGGL(k_main, dim3(512), dim3(256), 0, stream, xt, Am, para, out);
}